// Round 1
// baseline (45277.417 us; speedup 1.0000x reference)
//
#include <hip/hip_runtime.h>
#include <hip/hip_cooperative_groups.h>
#include <hip/hip_bf16.h>
#include <cstdint>
#include <cstddef>

namespace cg = cooperative_groups;

// ---------- types ----------
typedef __bf16 bf16x8 __attribute__((ext_vector_type(8)));
typedef float  f32x4  __attribute__((ext_vector_type(4)));

#define MFMA16(a, b, c) __builtin_amdgcn_mfma_f32_16x16x32_bf16((a), (b), (c), 0, 0, 0)

// async global->LDS, 16B per lane (wave-uniform base + lane*16 layout honored below)
#define ASYNC_CP16(gsrc, ldst)                                                              \
    __builtin_amdgcn_global_load_lds((const __attribute__((address_space(1))) void*)(gsrc), \
                                     (__attribute__((address_space(3))) void*)(ldst), 16, 0, 0)

// ---------- problem constants ----------
static constexpr int BN = 4, CN = 16, TN = 1000, FN = 96, HN = 64;
static constexpr int HID = 1536;          // C*F
static constexpr int INQ = 6144;          // H*F
static constexpr int G3  = 4608;          // 3*HID
static constexpr int MPAD = 4096;         // padded M for GEMM

// ---------- workspace layout (bytes) ----------
static constexpr size_t OFF_SEQ = 0;                           // bf16 [4096][6144]
static constexpr size_t OFF_WIH = 50331648;                    // bf16 [4608][6144]
static constexpr size_t OFF_GX  = OFF_WIH + 56623104;          // bf16 [4096][4608]
static constexpr size_t OFF_H   = OFF_GX + 37748736;           // bf16 [2][6144]

// =====================================================================
// Kernel 1: Wih fp32 -> bf16
// =====================================================================
__global__ __launch_bounds__(256) void cvt_wih_kernel(const float* __restrict__ W,
                                                      __bf16* __restrict__ Wb) {
    size_t i0 = ((size_t)blockIdx.x * 256 + threadIdx.x) * 4;
    size_t stride = (size_t)gridDim.x * 256 * 4;
    for (size_t i = i0; i < (size_t)G3 * INQ; i += stride) {
        float4 v = *(const float4*)(W + i);
        Wb[i + 0] = (__bf16)v.x;
        Wb[i + 1] = (__bf16)v.y;
        Wb[i + 2] = (__bf16)v.z;
        Wb[i + 3] = (__bf16)v.w;
    }
}

// =====================================================================
// Kernel 2: fused conv(q,k,v) + joint-softmax attention, one block per (b,t)
// writes seq bf16 row [f*64+h]; blocks >= 4000 zero the pad rows.
// =====================================================================
__global__ __launch_bounds__(256) void conv_attn_kernel(
    const float* __restrict__ x,
    const float* __restrict__ Wq, const float* __restrict__ bq,
    const float* __restrict__ Wk, const float* __restrict__ bk,
    const float* __restrict__ Wv, const float* __restrict__ bv,
    __bf16* __restrict__ seqB) {
    const int bt  = blockIdx.x;
    const int tid = threadIdx.x;
    __bf16* srow = seqB + (size_t)bt * INQ;
    if (bt >= BN * TN) {  // zero pad rows 4000..4095 (GEMM reads them)
        for (int i = tid; i < INQ; i += 256) srow[i] = (__bf16)0.f;
        return;
    }
    const int b = bt / TN, t = bt % TN;

    __shared__ union __attribute__((aligned(16))) {
        struct {
            __bf16 xcolT[96][64];   // [f][c*3+d], cols 48..63 zero
            __bf16 wls[64][64];     // [h][c*3+d], cols 48..63 zero (reloaded q/k/v)
        } c;
        __bf16 P[96][104];          // exp-weights [f][g] (overlays conv bufs)
    } u;
    __shared__ __attribute__((aligned(16))) __bf16 qT[96][72];   // [f][h]
    __shared__ __attribute__((aligned(16))) __bf16 kT[96][72];   // [g][h]
    __shared__ __attribute__((aligned(16))) __bf16 vhg[64][104]; // [h][g]
    __shared__ float red[8];

    const int lane = tid & 63, wv = tid >> 6;
    const int wm = wv >> 1, wn = wv & 1;
    const int n16 = lane & 15, quad = lane >> 4;

    // ---- build xcolT (im2col, freq-pad with 0) ----
    const float* xb = x + ((size_t)b * CN * TN + t) * FN;  // + c*TN*FN + f
    for (int idx = tid; idx < 96 * 64; idx += 256) {
        int f = idx >> 6, kk = idx & 63;
        float v = 0.f;
        if (kk < 48) {
            int c = kk / 3, d = kk % 3, fi = f + d - 1;
            if (fi >= 0 && fi < FN) v = xb[(size_t)c * TN * FN + fi];
        }
        u.c.xcolT[f][kk] = (__bf16)v;
    }

    auto load_w = [&](const float* W) {
        for (int idx = tid; idx < 64 * 64; idx += 256) {
            int h = idx >> 6, kk = idx & 63;
            u.c.wls[h][kk] = (__bf16)(kk < 48 ? W[h * 48 + kk] : 0.f);
        }
    };

    // conv producing transposed output [f][h] (for q and k)
    auto conv_T = [&](const float* bias, __bf16(*out)[72]) {
        f32x4 acc[3][2];
        for (int mt = 0; mt < 3; ++mt)
            for (int nt = 0; nt < 2; ++nt) acc[mt][nt] = f32x4{0.f, 0.f, 0.f, 0.f};
        #pragma unroll
        for (int ks = 0; ks < 2; ++ks) {
            bf16x8 a[3], bb[2];
            #pragma unroll
            for (int mt = 0; mt < 3; ++mt)
                a[mt] = *(const bf16x8*)&u.c.xcolT[(wm * 3 + mt) * 16 + n16][ks * 32 + quad * 8];
            #pragma unroll
            for (int nt = 0; nt < 2; ++nt)
                bb[nt] = *(const bf16x8*)&u.c.wls[(wn * 2 + nt) * 16 + n16][ks * 32 + quad * 8];
            #pragma unroll
            for (int mt = 0; mt < 3; ++mt)
                #pragma unroll
                for (int nt = 0; nt < 2; ++nt) acc[mt][nt] = MFMA16(a[mt], bb[nt], acc[mt][nt]);
        }
        #pragma unroll
        for (int mt = 0; mt < 3; ++mt)
            #pragma unroll
            for (int nt = 0; nt < 2; ++nt) {
                int h = (wn * 2 + nt) * 16 + n16;
                float bvv = bias[h];
                #pragma unroll
                for (int i = 0; i < 4; ++i) {
                    int f = (wm * 3 + mt) * 16 + quad * 4 + i;
                    out[f][h] = (__bf16)(acc[mt][nt][i] + bvv);
                }
            }
    };

    load_w(Wq);
    __syncthreads();
    conv_T(bq, qT);
    __syncthreads();
    load_w(Wk);
    __syncthreads();
    conv_T(bk, kT);
    __syncthreads();
    load_w(Wv);
    __syncthreads();
    {   // v: natural layout [h][f]
        f32x4 acc[2][3];
        for (int mt = 0; mt < 2; ++mt)
            for (int nt = 0; nt < 3; ++nt) acc[mt][nt] = f32x4{0.f, 0.f, 0.f, 0.f};
        #pragma unroll
        for (int ks = 0; ks < 2; ++ks) {
            bf16x8 a[2], bb[3];
            #pragma unroll
            for (int mt = 0; mt < 2; ++mt)
                a[mt] = *(const bf16x8*)&u.c.wls[(wm * 2 + mt) * 16 + n16][ks * 32 + quad * 8];
            #pragma unroll
            for (int nt = 0; nt < 3; ++nt)
                bb[nt] = *(const bf16x8*)&u.c.xcolT[(wn * 3 + nt) * 16 + n16][ks * 32 + quad * 8];
            #pragma unroll
            for (int mt = 0; mt < 2; ++mt)
                #pragma unroll
                for (int nt = 0; nt < 3; ++nt) acc[mt][nt] = MFMA16(a[mt], bb[nt], acc[mt][nt]);
        }
        #pragma unroll
        for (int mt = 0; mt < 2; ++mt)
            #pragma unroll
            for (int nt = 0; nt < 3; ++nt) {
                int f = (wn * 3 + nt) * 16 + n16;
                #pragma unroll
                for (int i = 0; i < 4; ++i) {
                    int h = (wm * 2 + mt) * 16 + quad * 4 + i;
                    vhg[h][f] = (__bf16)(acc[mt][nt][i] + bv[h]);
                }
            }
    }
    __syncthreads();

    // ---- S = qT*k / 8, joint softmax (keep S in registers) ----
    f32x4 sa[3][3];
    for (int mt = 0; mt < 3; ++mt)
        for (int nt = 0; nt < 3; ++nt) sa[mt][nt] = f32x4{0.f, 0.f, 0.f, 0.f};
    #pragma unroll
    for (int ks = 0; ks < 2; ++ks) {
        bf16x8 a[3], bb[3];
        #pragma unroll
        for (int mt = 0; mt < 3; ++mt)
            a[mt] = *(const bf16x8*)&qT[(wm * 3 + mt) * 16 + n16][ks * 32 + quad * 8];
        #pragma unroll
        for (int nt = 0; nt < 3; ++nt)
            bb[nt] = *(const bf16x8*)&kT[(wn * 3 + nt) * 16 + n16][ks * 32 + quad * 8];
        #pragma unroll
        for (int mt = 0; mt < 3; ++mt)
            #pragma unroll
            for (int nt = 0; nt < 3; ++nt) sa[mt][nt] = MFMA16(a[mt], bb[nt], sa[mt][nt]);
    }
    float mx = -1e30f;
    #pragma unroll
    for (int mt = 0; mt < 3; ++mt)
        #pragma unroll
        for (int nt = 0; nt < 3; ++nt)
            #pragma unroll
            for (int i = 0; i < 4; ++i) {
                float s = sa[mt][nt][i] * 0.125f;  // 1/sqrt(64)
                sa[mt][nt][i] = s;
                mx = fmaxf(mx, s);
            }
    #pragma unroll
    for (int m = 1; m < 64; m <<= 1) mx = fmaxf(mx, __shfl_xor(mx, m, 64));
    if (lane == 0) red[wv] = mx;
    __syncthreads();
    float M = fmaxf(fmaxf(red[0], red[1]), fmaxf(red[2], red[3]));
    float zs = 0.f;
    #pragma unroll
    for (int mt = 0; mt < 3; ++mt)
        #pragma unroll
        for (int nt = 0; nt < 3; ++nt) {
            int g = (wn * 3 + nt) * 16 + n16;
            #pragma unroll
            for (int i = 0; i < 4; ++i) {
                int f = (wm * 3 + mt) * 16 + quad * 4 + i;
                float e = __expf(sa[mt][nt][i] - M);
                zs += e;
                u.P[f][g] = (__bf16)e;
            }
        }
    #pragma unroll
    for (int m = 1; m < 64; m <<= 1) zs += __shfl_xor(zs, m, 64);
    if (lane == 0) red[4 + wv] = zs;
    __syncthreads();
    float zinv = 1.f / (red[4] + red[5] + red[6] + red[7]);

    // ---- PV: out[f][h] = sum_g P[f][g] * v[h][g] ----
    f32x4 pa[3][2];
    for (int mt = 0; mt < 3; ++mt)
        for (int nt = 0; nt < 2; ++nt) pa[mt][nt] = f32x4{0.f, 0.f, 0.f, 0.f};
    #pragma unroll
    for (int ks = 0; ks < 3; ++ks) {
        bf16x8 a[3], bb[2];
        #pragma unroll
        for (int mt = 0; mt < 3; ++mt)
            a[mt] = *(const bf16x8*)&u.P[(wm * 3 + mt) * 16 + n16][ks * 32 + quad * 8];
        #pragma unroll
        for (int nt = 0; nt < 2; ++nt)
            bb[nt] = *(const bf16x8*)&vhg[(wn * 2 + nt) * 16 + n16][ks * 32 + quad * 8];
        #pragma unroll
        for (int mt = 0; mt < 3; ++mt)
            #pragma unroll
            for (int nt = 0; nt < 2; ++nt) pa[mt][nt] = MFMA16(a[mt], bb[nt], pa[mt][nt]);
    }
    #pragma unroll
    for (int mt = 0; mt < 3; ++mt)
        #pragma unroll
        for (int nt = 0; nt < 2; ++nt) {
            int h = (wn * 2 + nt) * 16 + n16;
            #pragma unroll
            for (int i = 0; i < 4; ++i) {
                int f = (wm * 3 + mt) * 16 + quad * 4 + i;
                srow[f * 64 + h] = (__bf16)(pa[mt][nt][i] * zinv);
            }
        }
}

// =====================================================================
// Kernel 3: gx = seq @ Wih^T + bih   (m97-style 128x128 bf16 MFMA, B^T layout)
// =====================================================================
__global__ __launch_bounds__(256) void gemm_kernel(const __bf16* __restrict__ A,
                                                   const __bf16* __restrict__ Bw,
                                                   const float* __restrict__ bih,
                                                   __bf16* __restrict__ gx) {
    const int bn = blockIdx.x;  // 36 N-tiles
    const int bm = blockIdx.y;  // 32 M-tiles
    const int tid = threadIdx.x;
    __shared__ __attribute__((aligned(16))) __bf16 As[128 * 64];
    __shared__ __attribute__((aligned(16))) __bf16 Bs[128 * 64];
    const int lane = tid & 63, wv = tid >> 6, wm = wv >> 1, wn = wv & 1;
    const int n16 = lane & 15, quad = lane >> 4;

    const int r  = tid >> 3;         // staging row 0..31
    const int c8 = (tid & 7) * 8;    // staging col (elems)
    const __bf16* ag = A  + ((size_t)(bm * 128 + r)) * INQ + c8;
    const __bf16* bg = Bw + ((size_t)(bn * 128 + r)) * INQ + c8;
    __bf16* as_dst = As + r * 64 + c8;
    __bf16* bs_dst = Bs + r * 64 + c8;

    f32x4 acc[4][4];
    for (int mt = 0; mt < 4; ++mt)
        for (int nt = 0; nt < 4; ++nt) acc[mt][nt] = f32x4{0.f, 0.f, 0.f, 0.f};

    for (int kt = 0; kt < 96; ++kt) {
        #pragma unroll
        for (int i = 0; i < 4; ++i) {
            ASYNC_CP16(ag + (size_t)i * 32 * INQ, as_dst + i * 32 * 64);
            ASYNC_CP16(bg + (size_t)i * 32 * INQ, bs_dst + i * 32 * 64);
        }
        ag += 64;
        bg += 64;
        __syncthreads();
        #pragma unroll
        for (int kk = 0; kk < 2; ++kk) {
            bf16x8 af[4], bf[4];
            #pragma unroll
            for (int mt = 0; mt < 4; ++mt)
                af[mt] = *(const bf16x8*)&As[(wm * 64 + mt * 16 + n16) * 64 + kk * 32 + quad * 8];
            #pragma unroll
            for (int nt = 0; nt < 4; ++nt)
                bf[nt] = *(const bf16x8*)&Bs[(wn * 64 + nt * 16 + n16) * 64 + kk * 32 + quad * 8];
            #pragma unroll
            for (int mt = 0; mt < 4; ++mt)
                #pragma unroll
                for (int nt = 0; nt < 4; ++nt) acc[mt][nt] = MFMA16(af[mt], bf[nt], acc[mt][nt]);
        }
        __syncthreads();
    }
    #pragma unroll
    for (int nt = 0; nt < 4; ++nt) {
        int n = bn * 128 + wn * 64 + nt * 16 + n16;
        float bvv = bih[n];
        #pragma unroll
        for (int mt = 0; mt < 4; ++mt) {
            int m0 = bm * 128 + wm * 64 + mt * 16 + quad * 4;
            #pragma unroll
            for (int i = 0; i < 4; ++i)
                gx[(size_t)(m0 + i) * G3 + n] = (__bf16)(acc[mt][nt][i] + bvv);
        }
    }
}

// =====================================================================
// Kernel 4: persistent cooperative GRU scan.
// 384 blocks x 256 thr, block owns 4 hidden units (12 Whh rows in LDS, bf16).
// Per step: stage h (bf16) -> LDS, MFMA matvec (K split over 4 waves),
// gates fp32 (own h exact in regs), write h/out, grid.sync().
// =====================================================================
__global__ __launch_bounds__(256) void gru_kernel(const __bf16* __restrict__ gx,
                                                  const float* __restrict__ Whh,
                                                  const float* __restrict__ bhh,
                                                  const float* __restrict__ h0,
                                                  __bf16* __restrict__ hbuf,
                                                  float* __restrict__ out) {
    const int blk = blockIdx.x;   // 384
    const int tid = threadIdx.x;
    const int u0 = blk * 4;
    constexpr int LDW = 1560;     // padded row stride (elems), 16B aligned, bank-friendly
    __shared__ __attribute__((aligned(16))) __bf16 Wl[12][LDW];  // rows: gate*4+du
    __shared__ __attribute__((aligned(16))) __bf16 hl[4][LDW];   // [b][k]
    __shared__ float part[4][4][16];                             // [wave][batch][row j]

    // load Whh slice (fp32 -> bf16), once
    for (int idx = tid; idx < 12 * HID; idx += 256) {
        int j = idx / HID, cc = idx % HID;
        int g = j >> 2, du = j & 3;
        Wl[j][cc] = (__bf16)Whh[(size_t)(g * HID + u0 + du) * HID + cc];
    }
    // init hbuf[0] from h0 (distributed over first blocks)
    for (int i = blk * 256 + tid; i < INQ; i += 384 * 256) hbuf[i] = (__bf16)h0[i];

    float hreg = 0.f;
    const int gb = tid >> 2, gu = tid & 3;  // gate-thread batch / unit-offset (tid<16)
    if (tid < 16) hreg = h0[gb * HID + u0 + gu];

    cg::grid_group grid = cg::this_grid();
    grid.sync();

    const int lane = tid & 63, wvi = tid >> 6;
    const int n16 = lane & 15, quad = lane >> 4;
    const int kbase = wvi * 384;
    const int wr = (n16 < 12) ? n16 : 0;   // clamp: rows >=12 produce unused lanes
    const int hr = n16 & 3;                // clamp: A rows >=4 produce unused D rows

    for (int t = 0; t < TN; ++t) {
        const __bf16* hs = hbuf + (size_t)(t & 1) * INQ;
        #pragma unroll
        for (int i = tid; i < 768; i += 256) {   // 6144 elems as 8-wide chunks
            int bb = i / 192, cc = (i % 192) * 8;
            *(bf16x8*)&hl[bb][cc] = *(const bf16x8*)(hs + bb * HID + cc);
        }
        __syncthreads();

        f32x4 acc = f32x4{0.f, 0.f, 0.f, 0.f};
        #pragma unroll
        for (int ks = 0; ks < 12; ++ks) {
            int k = kbase + ks * 32 + quad * 8;
            bf16x8 av = *(const bf16x8*)&hl[hr][k];
            bf16x8 bv = *(const bf16x8*)&Wl[wr][k];
            acc = MFMA16(av, bv, acc);
        }
        if (quad == 0) {
            #pragma unroll
            for (int i = 0; i < 4; ++i) part[wvi][i][n16] = acc[i];
        }
        __syncthreads();

        if (tid < 16) {
            float gr = 0.f, gz = 0.f, gn = 0.f;
            #pragma unroll
            for (int w = 0; w < 4; ++w) {
                gr += part[w][gb][gu];
                gz += part[w][gb][4 + gu];
                gn += part[w][gb][8 + gu];
            }
            gr += bhh[u0 + gu];
            gz += bhh[HID + u0 + gu];
            gn += bhh[2 * HID + u0 + gu];
            const __bf16* gxr = gx + (size_t)(gb * TN + t) * G3;
            float xr = (float)gxr[u0 + gu];
            float xz = (float)gxr[HID + u0 + gu];
            float xn = (float)gxr[2 * HID + u0 + gu];
            float rr = 1.f / (1.f + __expf(-(xr + gr)));
            float zz = 1.f / (1.f + __expf(-(xz + gz)));
            float nn = tanhf(xn + rr * gn);
            float hn = (1.f - zz) * nn + zz * hreg;
            hreg = hn;
            hbuf[(size_t)((t + 1) & 1) * INQ + gb * HID + u0 + gu] = (__bf16)hn;
            int uu = u0 + gu;
            out[((size_t)(gb * CN + uu / FN) * TN + t) * FN + (uu % FN)] = hn;
        }
        grid.sync();
    }
    if (tid < 16) out[(size_t)BN * CN * TN * FN + gb * HID + u0 + gu] = hreg;
}

// =====================================================================
extern "C" void kernel_launch(void* const* d_in, const int* in_sizes, int n_in,
                              void* d_out, int out_size, void* d_ws, size_t ws_size,
                              hipStream_t stream) {
    const float* x   = (const float*)d_in[0];
    const float* h0  = (const float*)d_in[1];
    const float* Wq  = (const float*)d_in[2];
    const float* bq  = (const float*)d_in[3];
    const float* Wk  = (const float*)d_in[4];
    const float* bk  = (const float*)d_in[5];
    const float* Wv  = (const float*)d_in[6];
    const float* bv  = (const float*)d_in[7];
    const float* Wih = (const float*)d_in[8];
    const float* Whh = (const float*)d_in[9];
    const float* bih = (const float*)d_in[10];
    const float* bhh = (const float*)d_in[11];
    float* out = (float*)d_out;
    char* ws = (char*)d_ws;
    __bf16* seqB = (__bf16*)(ws + OFF_SEQ);
    __bf16* WihB = (__bf16*)(ws + OFF_WIH);
    __bf16* gxB  = (__bf16*)(ws + OFF_GX);
    __bf16* hbuf = (__bf16*)(ws + OFF_H);

    hipLaunchKernelGGL(cvt_wih_kernel, dim3(2048), dim3(256), 0, stream, Wih, WihB);
    hipLaunchKernelGGL(conv_attn_kernel, dim3(4096), dim3(256), 0, stream,
                       x, Wq, bq, Wk, bk, Wv, bv, seqB);
    hipLaunchKernelGGL(gemm_kernel, dim3(36, 32), dim3(256), 0, stream, seqB, WihB, bih, gxB);

    void* args[] = {(void*)&gxB, (void*)&Whh, (void*)&bhh, (void*)&h0, (void*)&hbuf, (void*)&out};
    hipLaunchCooperativeKernel((void*)gru_kernel, dim3(384), dim3(256), args, 0, stream);
}

// Round 2
// 11652.842 us; speedup vs baseline: 3.8855x; 3.8855x over previous
//
#include <hip/hip_runtime.h>
#include <hip/hip_bf16.h>
#include <cstdint>
#include <cstddef>

// ---------- types ----------
typedef __bf16 bf16x8 __attribute__((ext_vector_type(8)));
typedef float  f32x4  __attribute__((ext_vector_type(4)));

#define MFMA16(a, b, c) __builtin_amdgcn_mfma_f32_16x16x32_bf16((a), (b), (c), 0, 0, 0)

// async global->LDS, 16B per lane (wave-uniform base + lane*16 layout honored below)
#define ASYNC_CP16(gsrc, ldst)                                                              \
    __builtin_amdgcn_global_load_lds((const __attribute__((address_space(1))) void*)(gsrc), \
                                     (__attribute__((address_space(3))) void*)(ldst), 16, 0, 0)

// ---------- problem constants ----------
static constexpr int BN = 4, CN = 16, TN = 1000, FN = 96, HN = 64;
static constexpr int HID = 1536;          // C*F
static constexpr int INQ = 6144;          // H*F
static constexpr int G3  = 4608;          // 3*HID

// ---------- workspace layout (bytes) ----------
static constexpr size_t OFF_SEQ = 0;                           // bf16 [4096][6144]
static constexpr size_t OFF_WIH = 50331648;                    // bf16 [4608][6144]
static constexpr size_t OFF_GX  = OFF_WIH + 56623104;          // bf16 [4096][4608]
static constexpr size_t OFF_H   = OFF_GX + 37748736;           // bf16 [2][6144]
static constexpr size_t OFF_BAR = OFF_H + 32768;               // unsigned[10*32], zeroed per launch

// =====================================================================
// Kernel 1: Wih fp32 -> bf16
// =====================================================================
__global__ __launch_bounds__(256) void cvt_wih_kernel(const float* __restrict__ W,
                                                      __bf16* __restrict__ Wb) {
    size_t i0 = ((size_t)blockIdx.x * 256 + threadIdx.x) * 4;
    size_t stride = (size_t)gridDim.x * 256 * 4;
    for (size_t i = i0; i < (size_t)G3 * INQ; i += stride) {
        float4 v = *(const float4*)(W + i);
        Wb[i + 0] = (__bf16)v.x;
        Wb[i + 1] = (__bf16)v.y;
        Wb[i + 2] = (__bf16)v.z;
        Wb[i + 3] = (__bf16)v.w;
    }
}

// =====================================================================
// Kernel 2: fused conv(q,k,v) + joint-softmax attention, one block per (b,t)
// =====================================================================
__global__ __launch_bounds__(256) void conv_attn_kernel(
    const float* __restrict__ x,
    const float* __restrict__ Wq, const float* __restrict__ bq,
    const float* __restrict__ Wk, const float* __restrict__ bk,
    const float* __restrict__ Wv, const float* __restrict__ bv,
    __bf16* __restrict__ seqB) {
    const int bt  = blockIdx.x;
    const int tid = threadIdx.x;
    __bf16* srow = seqB + (size_t)bt * INQ;
    if (bt >= BN * TN) {  // zero pad rows 4000..4095 (GEMM reads them)
        for (int i = tid; i < INQ; i += 256) srow[i] = (__bf16)0.f;
        return;
    }
    const int b = bt / TN, t = bt % TN;

    __shared__ union __attribute__((aligned(16))) {
        struct {
            __bf16 xcolT[96][64];   // [f][c*3+d], cols 48..63 zero
            __bf16 wls[64][64];     // [h][c*3+d], cols 48..63 zero (reloaded q/k/v)
        } c;
        __bf16 P[96][104];          // exp-weights [f][g] (overlays conv bufs)
    } u;
    __shared__ __attribute__((aligned(16))) __bf16 qT[96][72];   // [f][h]
    __shared__ __attribute__((aligned(16))) __bf16 kT[96][72];   // [g][h]
    __shared__ __attribute__((aligned(16))) __bf16 vhg[64][104]; // [h][g]
    __shared__ float red[8];

    const int lane = tid & 63, wv = tid >> 6;
    const int wm = wv >> 1, wn = wv & 1;
    const int n16 = lane & 15, quad = lane >> 4;

    // ---- build xcolT (im2col, freq-pad with 0) ----
    const float* xb = x + ((size_t)b * CN * TN + t) * FN;  // + c*TN*FN + f
    for (int idx = tid; idx < 96 * 64; idx += 256) {
        int f = idx >> 6, kk = idx & 63;
        float v = 0.f;
        if (kk < 48) {
            int c = kk / 3, d = kk % 3, fi = f + d - 1;
            if (fi >= 0 && fi < FN) v = xb[(size_t)c * TN * FN + fi];
        }
        u.c.xcolT[f][kk] = (__bf16)v;
    }

    auto load_w = [&](const float* W) {
        for (int idx = tid; idx < 64 * 64; idx += 256) {
            int h = idx >> 6, kk = idx & 63;
            u.c.wls[h][kk] = (__bf16)(kk < 48 ? W[h * 48 + kk] : 0.f);
        }
    };

    // conv producing transposed output [f][h] (for q and k)
    auto conv_T = [&](const float* bias, __bf16(*out)[72]) {
        f32x4 acc[3][2];
        for (int mt = 0; mt < 3; ++mt)
            for (int nt = 0; nt < 2; ++nt) acc[mt][nt] = f32x4{0.f, 0.f, 0.f, 0.f};
        #pragma unroll
        for (int ks = 0; ks < 2; ++ks) {
            bf16x8 a[3], bb[2];
            #pragma unroll
            for (int mt = 0; mt < 3; ++mt)
                a[mt] = *(const bf16x8*)&u.c.xcolT[(wm * 3 + mt) * 16 + n16][ks * 32 + quad * 8];
            #pragma unroll
            for (int nt = 0; nt < 2; ++nt)
                bb[nt] = *(const bf16x8*)&u.c.wls[(wn * 2 + nt) * 16 + n16][ks * 32 + quad * 8];
            #pragma unroll
            for (int mt = 0; mt < 3; ++mt)
                #pragma unroll
                for (int nt = 0; nt < 2; ++nt) acc[mt][nt] = MFMA16(a[mt], bb[nt], acc[mt][nt]);
        }
        #pragma unroll
        for (int mt = 0; mt < 3; ++mt)
            #pragma unroll
            for (int nt = 0; nt < 2; ++nt) {
                int h = (wn * 2 + nt) * 16 + n16;
                float bvv = bias[h];
                #pragma unroll
                for (int i = 0; i < 4; ++i) {
                    int f = (wm * 3 + mt) * 16 + quad * 4 + i;
                    out[f][h] = (__bf16)(acc[mt][nt][i] + bvv);
                }
            }
    };

    load_w(Wq);
    __syncthreads();
    conv_T(bq, qT);
    __syncthreads();
    load_w(Wk);
    __syncthreads();
    conv_T(bk, kT);
    __syncthreads();
    load_w(Wv);
    __syncthreads();
    {   // v: natural layout [h][f]
        f32x4 acc[2][3];
        for (int mt = 0; mt < 2; ++mt)
            for (int nt = 0; nt < 3; ++nt) acc[mt][nt] = f32x4{0.f, 0.f, 0.f, 0.f};
        #pragma unroll
        for (int ks = 0; ks < 2; ++ks) {
            bf16x8 a[2], bb[3];
            #pragma unroll
            for (int mt = 0; mt < 2; ++mt)
                a[mt] = *(const bf16x8*)&u.c.wls[(wm * 2 + mt) * 16 + n16][ks * 32 + quad * 8];
            #pragma unroll
            for (int nt = 0; nt < 3; ++nt)
                bb[nt] = *(const bf16x8*)&u.c.xcolT[(wn * 3 + nt) * 16 + n16][ks * 32 + quad * 8];
            #pragma unroll
            for (int mt = 0; mt < 2; ++mt)
                #pragma unroll
                for (int nt = 0; nt < 3; ++nt) acc[mt][nt] = MFMA16(a[mt], bb[nt], acc[mt][nt]);
        }
        #pragma unroll
        for (int mt = 0; mt < 2; ++mt)
            #pragma unroll
            for (int nt = 0; nt < 3; ++nt) {
                int f = (wn * 3 + nt) * 16 + n16;
                #pragma unroll
                for (int i = 0; i < 4; ++i) {
                    int h = (wm * 2 + mt) * 16 + quad * 4 + i;
                    vhg[h][f] = (__bf16)(acc[mt][nt][i] + bv[h]);
                }
            }
    }
    __syncthreads();

    // ---- S = qT*k / 8, joint softmax (keep S in registers) ----
    f32x4 sa[3][3];
    for (int mt = 0; mt < 3; ++mt)
        for (int nt = 0; nt < 3; ++nt) sa[mt][nt] = f32x4{0.f, 0.f, 0.f, 0.f};
    #pragma unroll
    for (int ks = 0; ks < 2; ++ks) {
        bf16x8 a[3], bb[3];
        #pragma unroll
        for (int mt = 0; mt < 3; ++mt)
            a[mt] = *(const bf16x8*)&qT[(wm * 3 + mt) * 16 + n16][ks * 32 + quad * 8];
        #pragma unroll
        for (int nt = 0; nt < 3; ++nt)
            bb[nt] = *(const bf16x8*)&kT[(wn * 3 + nt) * 16 + n16][ks * 32 + quad * 8];
        #pragma unroll
        for (int mt = 0; mt < 3; ++mt)
            #pragma unroll
            for (int nt = 0; nt < 3; ++nt) sa[mt][nt] = MFMA16(a[mt], bb[nt], sa[mt][nt]);
    }
    float mx = -1e30f;
    #pragma unroll
    for (int mt = 0; mt < 3; ++mt)
        #pragma unroll
        for (int nt = 0; nt < 3; ++nt)
            #pragma unroll
            for (int i = 0; i < 4; ++i) {
                float s = sa[mt][nt][i] * 0.125f;  // 1/sqrt(64)
                sa[mt][nt][i] = s;
                mx = fmaxf(mx, s);
            }
    #pragma unroll
    for (int m = 1; m < 64; m <<= 1) mx = fmaxf(mx, __shfl_xor(mx, m, 64));
    if (lane == 0) red[wv] = mx;
    __syncthreads();
    float M = fmaxf(fmaxf(red[0], red[1]), fmaxf(red[2], red[3]));
    float zs = 0.f;
    #pragma unroll
    for (int mt = 0; mt < 3; ++mt)
        #pragma unroll
        for (int nt = 0; nt < 3; ++nt) {
            int g = (wn * 3 + nt) * 16 + n16;
            #pragma unroll
            for (int i = 0; i < 4; ++i) {
                int f = (wm * 3 + mt) * 16 + quad * 4 + i;
                float e = __expf(sa[mt][nt][i] - M);
                zs += e;
                u.P[f][g] = (__bf16)e;
            }
        }
    #pragma unroll
    for (int m = 1; m < 64; m <<= 1) zs += __shfl_xor(zs, m, 64);
    if (lane == 0) red[4 + wv] = zs;
    __syncthreads();
    float zinv = 1.f / (red[4] + red[5] + red[6] + red[7]);

    // ---- PV: out[f][h] = sum_g P[f][g] * v[h][g] ----
    f32x4 pa[3][2];
    for (int mt = 0; mt < 3; ++mt)
        for (int nt = 0; nt < 2; ++nt) pa[mt][nt] = f32x4{0.f, 0.f, 0.f, 0.f};
    #pragma unroll
    for (int ks = 0; ks < 3; ++ks) {
        bf16x8 a[3], bb[2];
        #pragma unroll
        for (int mt = 0; mt < 3; ++mt)
            a[mt] = *(const bf16x8*)&u.P[(wm * 3 + mt) * 16 + n16][ks * 32 + quad * 8];
        #pragma unroll
        for (int nt = 0; nt < 2; ++nt)
            bb[nt] = *(const bf16x8*)&vhg[(wn * 2 + nt) * 16 + n16][ks * 32 + quad * 8];
        #pragma unroll
        for (int mt = 0; mt < 3; ++mt)
            #pragma unroll
            for (int nt = 0; nt < 2; ++nt) pa[mt][nt] = MFMA16(a[mt], bb[nt], pa[mt][nt]);
    }
    #pragma unroll
    for (int mt = 0; mt < 3; ++mt)
        #pragma unroll
        for (int nt = 0; nt < 2; ++nt) {
            int h = (wn * 2 + nt) * 16 + n16;
            #pragma unroll
            for (int i = 0; i < 4; ++i) {
                int f = (wm * 3 + mt) * 16 + quad * 4 + i;
                srow[f * 64 + h] = (__bf16)(pa[mt][nt][i] * zinv);
            }
        }
}

// =====================================================================
// Kernel 3: gx = seq @ Wih^T + bih   (m97-style 128x128 bf16 MFMA, B^T layout)
// =====================================================================
__global__ __launch_bounds__(256) void gemm_kernel(const __bf16* __restrict__ A,
                                                   const __bf16* __restrict__ Bw,
                                                   const float* __restrict__ bih,
                                                   __bf16* __restrict__ gx) {
    const int bn = blockIdx.x;  // 36 N-tiles
    const int bm = blockIdx.y;  // 32 M-tiles
    const int tid = threadIdx.x;
    __shared__ __attribute__((aligned(16))) __bf16 As[128 * 64];
    __shared__ __attribute__((aligned(16))) __bf16 Bs[128 * 64];
    const int lane = tid & 63, wv = tid >> 6, wm = wv >> 1, wn = wv & 1;
    const int n16 = lane & 15, quad = lane >> 4;

    const int r  = tid >> 3;         // staging row 0..31
    const int c8 = (tid & 7) * 8;    // staging col (elems)
    const __bf16* ag = A  + ((size_t)(bm * 128 + r)) * INQ + c8;
    const __bf16* bg = Bw + ((size_t)(bn * 128 + r)) * INQ + c8;
    __bf16* as_dst = As + r * 64 + c8;
    __bf16* bs_dst = Bs + r * 64 + c8;

    f32x4 acc[4][4];
    for (int mt = 0; mt < 4; ++mt)
        for (int nt = 0; nt < 4; ++nt) acc[mt][nt] = f32x4{0.f, 0.f, 0.f, 0.f};

    for (int kt = 0; kt < 96; ++kt) {
        #pragma unroll
        for (int i = 0; i < 4; ++i) {
            ASYNC_CP16(ag + (size_t)i * 32 * INQ, as_dst + i * 32 * 64);
            ASYNC_CP16(bg + (size_t)i * 32 * INQ, bs_dst + i * 32 * 64);
        }
        ag += 64;
        bg += 64;
        __syncthreads();
        #pragma unroll
        for (int kk = 0; kk < 2; ++kk) {
            bf16x8 af[4], bf[4];
            #pragma unroll
            for (int mt = 0; mt < 4; ++mt)
                af[mt] = *(const bf16x8*)&As[(wm * 64 + mt * 16 + n16) * 64 + kk * 32 + quad * 8];
            #pragma unroll
            for (int nt = 0; nt < 4; ++nt)
                bf[nt] = *(const bf16x8*)&Bs[(wn * 64 + nt * 16 + n16) * 64 + kk * 32 + quad * 8];
            #pragma unroll
            for (int mt = 0; mt < 4; ++mt)
                #pragma unroll
                for (int nt = 0; nt < 4; ++nt) acc[mt][nt] = MFMA16(af[mt], bf[nt], acc[mt][nt]);
        }
        __syncthreads();
    }
    #pragma unroll
    for (int nt = 0; nt < 4; ++nt) {
        int n = bn * 128 + wn * 64 + nt * 16 + n16;
        float bvv = bih[n];
        #pragma unroll
        for (int mt = 0; mt < 4; ++mt) {
            int m0 = bm * 128 + wm * 64 + mt * 16 + quad * 4;
            #pragma unroll
            for (int i = 0; i < 4; ++i)
                gx[(size_t)(m0 + i) * G3 + n] = (__bf16)(acc[mt][nt][i] + bvv);
        }
    }
}

// =====================================================================
// Kernel 4: persistent GRU scan with hand-rolled two-level device barrier.
// 384 blocks x 256 thr, block owns 4 hidden units (12 Whh rows in LDS, bf16).
// bar layout (unsigned, 128B-strided lines): cnt[8] @ i*32, master @ 8*32, gen @ 9*32
// =====================================================================
__global__ __launch_bounds__(256) void gru_kernel(const __bf16* __restrict__ gx,
                                                  const float* __restrict__ Whh,
                                                  const float* __restrict__ bhh,
                                                  const float* __restrict__ h0,
                                                  __bf16* __restrict__ hbuf,
                                                  unsigned* __restrict__ bar,
                                                  float* __restrict__ out) {
    const int blk = blockIdx.x;   // 384
    const int tid = threadIdx.x;
    const int u0 = blk * 4;
    constexpr int LDW = 1560;     // padded row stride (elems)
    __shared__ __attribute__((aligned(16))) __bf16 Wl[12][LDW];  // rows: gate*4+du
    __shared__ __attribute__((aligned(16))) __bf16 hl[4][LDW];   // [b][k]
    __shared__ float part[4][4][16];                             // [wave][batch][row j]

    unsigned* cnt    = bar + (blk & 7) * 32;
    unsigned* master = bar + 8 * 32;
    unsigned* genp   = bar + 9 * 32;

    // barrier: generation g (1-based, monotone). All threads return after gen>=g.
    auto bar_sync = [&](unsigned g) {
        __syncthreads();   // all block's prior work done before arrive
        if (tid == 0) {
            __builtin_amdgcn_fence(__ATOMIC_RELEASE, "agent");
            unsigned old = __hip_atomic_fetch_add(cnt, 1u, __ATOMIC_RELAXED,
                                                  __HIP_MEMORY_SCOPE_AGENT);
            if (old + 1 == 48u * g) {
                unsigned mo = __hip_atomic_fetch_add(master, 1u, __ATOMIC_RELAXED,
                                                     __HIP_MEMORY_SCOPE_AGENT);
                if (mo + 1 == 8u * g)
                    __hip_atomic_store(genp, g, __ATOMIC_RELAXED, __HIP_MEMORY_SCOPE_AGENT);
            }
            while (__hip_atomic_load(genp, __ATOMIC_RELAXED, __HIP_MEMORY_SCOPE_AGENT) < g)
                __builtin_amdgcn_s_sleep(1);
            __builtin_amdgcn_fence(__ATOMIC_ACQUIRE, "agent");
        }
        __syncthreads();
    };

    // load Whh slice (fp32 -> bf16), once
    for (int idx = tid; idx < 12 * HID; idx += 256) {
        int j = idx / HID, cc = idx % HID;
        int g = j >> 2, du = j & 3;
        Wl[j][cc] = (__bf16)Whh[(size_t)(g * HID + u0 + du) * HID + cc];
    }
    // init hbuf[0] from h0 (distributed over first blocks)
    for (int i = blk * 256 + tid; i < INQ; i += 384 * 256) hbuf[i] = (__bf16)h0[i];

    float hreg = 0.f;
    const int gb = tid >> 2, gu = tid & 3;  // gate-thread batch / unit-offset (tid<16)
    if (tid < 16) hreg = h0[gb * HID + u0 + gu];

    bar_sync(1);

    const int lane = tid & 63, wvi = tid >> 6;
    const int n16 = lane & 15, quad = lane >> 4;
    const int kbase = wvi * 384;
    const int wr = (n16 < 12) ? n16 : 0;   // clamp: rows >=12 produce unused lanes
    const int hr = n16 & 3;                // clamp: A rows >=4 produce unused D rows

    for (int t = 0; t < TN; ++t) {
        const __bf16* hs = hbuf + (size_t)(t & 1) * INQ;
        #pragma unroll
        for (int i = tid; i < 768; i += 256) {   // 6144 elems as 8-wide chunks
            int bb = i / 192, cc = (i % 192) * 8;
            *(bf16x8*)&hl[bb][cc] = *(const bf16x8*)(hs + bb * HID + cc);
        }
        __syncthreads();

        f32x4 acc = f32x4{0.f, 0.f, 0.f, 0.f};
        #pragma unroll
        for (int ks = 0; ks < 12; ++ks) {
            int k = kbase + ks * 32 + quad * 8;
            bf16x8 av = *(const bf16x8*)&hl[hr][k];
            bf16x8 bv = *(const bf16x8*)&Wl[wr][k];
            acc = MFMA16(av, bv, acc);
        }
        if (quad == 0) {
            #pragma unroll
            for (int i = 0; i < 4; ++i) part[wvi][i][n16] = acc[i];
        }
        __syncthreads();

        if (tid < 16) {
            float gr = 0.f, gz = 0.f, gn = 0.f;
            #pragma unroll
            for (int w = 0; w < 4; ++w) {
                gr += part[w][gb][gu];
                gz += part[w][gb][4 + gu];
                gn += part[w][gb][8 + gu];
            }
            gr += bhh[u0 + gu];
            gz += bhh[HID + u0 + gu];
            gn += bhh[2 * HID + u0 + gu];
            const __bf16* gxr = gx + (size_t)(gb * TN + t) * G3;
            float xr = (float)gxr[u0 + gu];
            float xz = (float)gxr[HID + u0 + gu];
            float xn = (float)gxr[2 * HID + u0 + gu];
            float rr = 1.f / (1.f + __expf(-(xr + gr)));
            float zz = 1.f / (1.f + __expf(-(xz + gz)));
            float nn = tanhf(xn + rr * gn);
            float hn = (1.f - zz) * nn + zz * hreg;
            hreg = hn;
            hbuf[(size_t)((t + 1) & 1) * INQ + gb * HID + u0 + gu] = (__bf16)hn;
            int uu = u0 + gu;
            out[((size_t)(gb * CN + uu / FN) * TN + t) * FN + (uu % FN)] = hn;
        }
        bar_sync((unsigned)(t + 2));
    }
    if (tid < 16) out[(size_t)BN * CN * TN * FN + gb * HID + u0 + gu] = hreg;
}

// =====================================================================
extern "C" void kernel_launch(void* const* d_in, const int* in_sizes, int n_in,
                              void* d_out, int out_size, void* d_ws, size_t ws_size,
                              hipStream_t stream) {
    const float* x   = (const float*)d_in[0];
    const float* h0  = (const float*)d_in[1];
    const float* Wq  = (const float*)d_in[2];
    const float* bq  = (const float*)d_in[3];
    const float* Wk  = (const float*)d_in[4];
    const float* bk  = (const float*)d_in[5];
    const float* Wv  = (const float*)d_in[6];
    const float* bv  = (const float*)d_in[7];
    const float* Wih = (const float*)d_in[8];
    const float* Whh = (const float*)d_in[9];
    const float* bih = (const float*)d_in[10];
    const float* bhh = (const float*)d_in[11];
    float* out = (float*)d_out;
    char* ws = (char*)d_ws;
    __bf16* seqB = (__bf16*)(ws + OFF_SEQ);
    __bf16* WihB = (__bf16*)(ws + OFF_WIH);
    __bf16* gxB  = (__bf16*)(ws + OFF_GX);
    __bf16* hbuf = (__bf16*)(ws + OFF_H);
    unsigned* bar = (unsigned*)(ws + OFF_BAR);

    hipMemsetAsync((void*)bar, 0, 4096, stream);  // zero barrier state every launch
    hipLaunchKernelGGL(cvt_wih_kernel, dim3(2048), dim3(256), 0, stream, Wih, WihB);
    hipLaunchKernelGGL(conv_attn_kernel, dim3(4096), dim3(256), 0, stream,
                       x, Wq, bq, Wk, bk, Wv, bv, seqB);
    hipLaunchKernelGGL(gemm_kernel, dim3(36, 32), dim3(256), 0, stream, seqB, WihB, bih, gxB);

    void* args[] = {(void*)&gxB, (void*)&Whh, (void*)&bhh, (void*)&h0,
                    (void*)&hbuf, (void*)&bar, (void*)&out};
    hipLaunchCooperativeKernel((void*)gru_kernel, dim3(384), dim3(256), args, 0, stream);
}

// Round 3
// 5292.981 us; speedup vs baseline: 8.5542x; 2.2016x over previous
//
#include <hip/hip_runtime.h>
#include <hip/hip_bf16.h>
#include <cstdint>
#include <cstddef>

// ---------- types ----------
typedef __bf16 bf16x8 __attribute__((ext_vector_type(8)));
typedef float  f32x4  __attribute__((ext_vector_type(4)));
typedef unsigned long long u64;

#define MFMA16(a, b, c) __builtin_amdgcn_mfma_f32_16x16x32_bf16((a), (b), (c), 0, 0, 0)

// async global->LDS, 16B per lane (wave-uniform base + lane*16 layout honored below)
#define ASYNC_CP16(gsrc, ldst)                                                              \
    __builtin_amdgcn_global_load_lds((const __attribute__((address_space(1))) void*)(gsrc), \
                                     (__attribute__((address_space(3))) void*)(ldst), 16, 0, 0)

// ---------- problem constants ----------
static constexpr int BN = 4, CN = 16, TN = 1000, FN = 96, HN = 64;
static constexpr int HID = 1536;          // C*F
static constexpr int INQ = 6144;          // H*F
static constexpr int G3  = 4608;          // 3*HID

// ---------- workspace layout (bytes) ----------
static constexpr size_t OFF_SEQ = 0;                           // bf16 [4096][6144]
static constexpr size_t OFF_WIH = 50331648;                    // bf16 [4608][6144]
static constexpr size_t OFF_GX  = OFF_WIH + 56623104;          // bf16 [4096][4608]
static constexpr size_t OFF_H   = OFF_GX + 37748736;           // bf16 [2][6144]
static constexpr size_t OFF_BAR = OFF_H + 32768;               // unsigned[18*32], zeroed per launch

__device__ inline u64 pack4bf(float a, float b, float c, float d) {
    union { __bf16 h; unsigned short u; } x;
    u64 p;
    x.h = (__bf16)a; p = x.u;
    x.h = (__bf16)b; p |= (u64)x.u << 16;
    x.h = (__bf16)c; p |= (u64)x.u << 32;
    x.h = (__bf16)d; p |= (u64)x.u << 48;
    return p;
}

// =====================================================================
// Kernel 1: Wih fp32 -> bf16
// =====================================================================
__global__ __launch_bounds__(256) void cvt_wih_kernel(const float* __restrict__ W,
                                                      __bf16* __restrict__ Wb) {
    size_t i0 = ((size_t)blockIdx.x * 256 + threadIdx.x) * 4;
    size_t stride = (size_t)gridDim.x * 256 * 4;
    for (size_t i = i0; i < (size_t)G3 * INQ; i += stride) {
        float4 v = *(const float4*)(W + i);
        Wb[i + 0] = (__bf16)v.x;
        Wb[i + 1] = (__bf16)v.y;
        Wb[i + 2] = (__bf16)v.z;
        Wb[i + 3] = (__bf16)v.w;
    }
}

// =====================================================================
// Kernel 2: fused conv(q,k,v) + joint-softmax attention, one block per (b,t)
// =====================================================================
__global__ __launch_bounds__(256) void conv_attn_kernel(
    const float* __restrict__ x,
    const float* __restrict__ Wq, const float* __restrict__ bq,
    const float* __restrict__ Wk, const float* __restrict__ bk,
    const float* __restrict__ Wv, const float* __restrict__ bv,
    __bf16* __restrict__ seqB) {
    const int bt  = blockIdx.x;
    const int tid = threadIdx.x;
    __bf16* srow = seqB + (size_t)bt * INQ;
    if (bt >= BN * TN) {  // zero pad rows 4000..4095 (GEMM reads them)
        for (int i = tid; i < INQ; i += 256) srow[i] = (__bf16)0.f;
        return;
    }
    const int b = bt / TN, t = bt % TN;

    __shared__ union __attribute__((aligned(16))) {
        struct {
            __bf16 xcolT[96][64];   // [f][c*3+d], cols 48..63 zero
            __bf16 wls[64][64];     // [h][c*3+d], cols 48..63 zero (reloaded q/k/v)
        } c;
        __bf16 P[96][104];          // exp-weights [f][g] (overlays conv bufs)
    } u;
    __shared__ __attribute__((aligned(16))) __bf16 qT[96][72];   // [f][h]
    __shared__ __attribute__((aligned(16))) __bf16 kT[96][72];   // [g][h]
    __shared__ __attribute__((aligned(16))) __bf16 vhg[64][104]; // [h][g]
    __shared__ float red[8];

    const int lane = tid & 63, wv = tid >> 6;
    const int wm = wv >> 1, wn = wv & 1;
    const int n16 = lane & 15, quad = lane >> 4;

    // ---- build xcolT (im2col, freq-pad with 0) ----
    const float* xb = x + ((size_t)b * CN * TN + t) * FN;  // + c*TN*FN + f
    for (int idx = tid; idx < 96 * 64; idx += 256) {
        int f = idx >> 6, kk = idx & 63;
        float v = 0.f;
        if (kk < 48) {
            int c = kk / 3, d = kk % 3, fi = f + d - 1;
            if (fi >= 0 && fi < FN) v = xb[(size_t)c * TN * FN + fi];
        }
        u.c.xcolT[f][kk] = (__bf16)v;
    }

    auto load_w = [&](const float* W) {
        for (int idx = tid; idx < 64 * 64; idx += 256) {
            int h = idx >> 6, kk = idx & 63;
            u.c.wls[h][kk] = (__bf16)(kk < 48 ? W[h * 48 + kk] : 0.f);
        }
    };

    // conv producing transposed output [f][h] (for q and k)
    auto conv_T = [&](const float* bias, __bf16(*out)[72]) {
        f32x4 acc[3][2];
        for (int mt = 0; mt < 3; ++mt)
            for (int nt = 0; nt < 2; ++nt) acc[mt][nt] = f32x4{0.f, 0.f, 0.f, 0.f};
        #pragma unroll
        for (int ks = 0; ks < 2; ++ks) {
            bf16x8 a[3], bb[2];
            #pragma unroll
            for (int mt = 0; mt < 3; ++mt)
                a[mt] = *(const bf16x8*)&u.c.xcolT[(wm * 3 + mt) * 16 + n16][ks * 32 + quad * 8];
            #pragma unroll
            for (int nt = 0; nt < 2; ++nt)
                bb[nt] = *(const bf16x8*)&u.c.wls[(wn * 2 + nt) * 16 + n16][ks * 32 + quad * 8];
            #pragma unroll
            for (int mt = 0; mt < 3; ++mt)
                #pragma unroll
                for (int nt = 0; nt < 2; ++nt) acc[mt][nt] = MFMA16(a[mt], bb[nt], acc[mt][nt]);
        }
        #pragma unroll
        for (int mt = 0; mt < 3; ++mt)
            #pragma unroll
            for (int nt = 0; nt < 2; ++nt) {
                int h = (wn * 2 + nt) * 16 + n16;
                float bvv = bias[h];
                #pragma unroll
                for (int i = 0; i < 4; ++i) {
                    int f = (wm * 3 + mt) * 16 + quad * 4 + i;
                    out[f][h] = (__bf16)(acc[mt][nt][i] + bvv);
                }
            }
    };

    load_w(Wq);
    __syncthreads();
    conv_T(bq, qT);
    __syncthreads();
    load_w(Wk);
    __syncthreads();
    conv_T(bk, kT);
    __syncthreads();
    load_w(Wv);
    __syncthreads();
    {   // v: natural layout [h][f]
        f32x4 acc[2][3];
        for (int mt = 0; mt < 2; ++mt)
            for (int nt = 0; nt < 3; ++nt) acc[mt][nt] = f32x4{0.f, 0.f, 0.f, 0.f};
        #pragma unroll
        for (int ks = 0; ks < 2; ++ks) {
            bf16x8 a[2], bb[3];
            #pragma unroll
            for (int mt = 0; mt < 2; ++mt)
                a[mt] = *(const bf16x8*)&u.c.wls[(wm * 2 + mt) * 16 + n16][ks * 32 + quad * 8];
            #pragma unroll
            for (int nt = 0; nt < 3; ++nt)
                bb[nt] = *(const bf16x8*)&u.c.xcolT[(wn * 3 + nt) * 16 + n16][ks * 32 + quad * 8];
            #pragma unroll
            for (int mt = 0; mt < 2; ++mt)
                #pragma unroll
                for (int nt = 0; nt < 3; ++nt) acc[mt][nt] = MFMA16(a[mt], bb[nt], acc[mt][nt]);
        }
        #pragma unroll
        for (int mt = 0; mt < 2; ++mt)
            #pragma unroll
            for (int nt = 0; nt < 3; ++nt) {
                int f = (wn * 3 + nt) * 16 + n16;
                #pragma unroll
                for (int i = 0; i < 4; ++i) {
                    int h = (wm * 2 + mt) * 16 + quad * 4 + i;
                    vhg[h][f] = (__bf16)(acc[mt][nt][i] + bv[h]);
                }
            }
    }
    __syncthreads();

    // ---- S = qT*k / 8, joint softmax (keep S in registers) ----
    f32x4 sa[3][3];
    for (int mt = 0; mt < 3; ++mt)
        for (int nt = 0; nt < 3; ++nt) sa[mt][nt] = f32x4{0.f, 0.f, 0.f, 0.f};
    #pragma unroll
    for (int ks = 0; ks < 2; ++ks) {
        bf16x8 a[3], bb[3];
        #pragma unroll
        for (int mt = 0; mt < 3; ++mt)
            a[mt] = *(const bf16x8*)&qT[(wm * 3 + mt) * 16 + n16][ks * 32 + quad * 8];
        #pragma unroll
        for (int nt = 0; nt < 3; ++nt)
            bb[nt] = *(const bf16x8*)&kT[(wn * 3 + nt) * 16 + n16][ks * 32 + quad * 8];
        #pragma unroll
        for (int mt = 0; mt < 3; ++mt)
            #pragma unroll
            for (int nt = 0; nt < 3; ++nt) sa[mt][nt] = MFMA16(a[mt], bb[nt], sa[mt][nt]);
    }
    float mx = -1e30f;
    #pragma unroll
    for (int mt = 0; mt < 3; ++mt)
        #pragma unroll
        for (int nt = 0; nt < 3; ++nt)
            #pragma unroll
            for (int i = 0; i < 4; ++i) {
                float s = sa[mt][nt][i] * 0.125f;  // 1/sqrt(64)
                sa[mt][nt][i] = s;
                mx = fmaxf(mx, s);
            }
    #pragma unroll
    for (int m = 1; m < 64; m <<= 1) mx = fmaxf(mx, __shfl_xor(mx, m, 64));
    if (lane == 0) red[wv] = mx;
    __syncthreads();
    float M = fmaxf(fmaxf(red[0], red[1]), fmaxf(red[2], red[3]));
    float zs = 0.f;
    #pragma unroll
    for (int mt = 0; mt < 3; ++mt)
        #pragma unroll
        for (int nt = 0; nt < 3; ++nt) {
            int g = (wn * 3 + nt) * 16 + n16;
            #pragma unroll
            for (int i = 0; i < 4; ++i) {
                int f = (wm * 3 + mt) * 16 + quad * 4 + i;
                float e = __expf(sa[mt][nt][i] - M);
                zs += e;
                u.P[f][g] = (__bf16)e;
            }
        }
    #pragma unroll
    for (int m = 1; m < 64; m <<= 1) zs += __shfl_xor(zs, m, 64);
    if (lane == 0) red[4 + wv] = zs;
    __syncthreads();
    float zinv = 1.f / (red[4] + red[5] + red[6] + red[7]);

    // ---- PV: out[f][h] = sum_g P[f][g] * v[h][g] ----
    f32x4 pa[3][2];
    for (int mt = 0; mt < 3; ++mt)
        for (int nt = 0; nt < 2; ++nt) pa[mt][nt] = f32x4{0.f, 0.f, 0.f, 0.f};
    #pragma unroll
    for (int ks = 0; ks < 3; ++ks) {
        bf16x8 a[3], bb[2];
        #pragma unroll
        for (int mt = 0; mt < 3; ++mt)
            a[mt] = *(const bf16x8*)&u.P[(wm * 3 + mt) * 16 + n16][ks * 32 + quad * 8];
        #pragma unroll
        for (int nt = 0; nt < 2; ++nt)
            bb[nt] = *(const bf16x8*)&vhg[(wn * 2 + nt) * 16 + n16][ks * 32 + quad * 8];
        #pragma unroll
        for (int mt = 0; mt < 3; ++mt)
            #pragma unroll
            for (int nt = 0; nt < 2; ++nt) pa[mt][nt] = MFMA16(a[mt], bb[nt], pa[mt][nt]);
    }
    #pragma unroll
    for (int mt = 0; mt < 3; ++mt)
        #pragma unroll
        for (int nt = 0; nt < 2; ++nt) {
            int h = (wn * 2 + nt) * 16 + n16;
            #pragma unroll
            for (int i = 0; i < 4; ++i) {
                int f = (wm * 3 + mt) * 16 + quad * 4 + i;
                srow[f * 64 + h] = (__bf16)(pa[mt][nt][i] * zinv);
            }
        }
}

// =====================================================================
// Kernel 3: gx = seq @ Wih^T + bih   (m97-style 128x128 bf16 MFMA, B^T layout)
// =====================================================================
__global__ __launch_bounds__(256) void gemm_kernel(const __bf16* __restrict__ A,
                                                   const __bf16* __restrict__ Bw,
                                                   const float* __restrict__ bih,
                                                   __bf16* __restrict__ gx) {
    const int bn = blockIdx.x;  // 36 N-tiles
    const int bm = blockIdx.y;  // 32 M-tiles
    const int tid = threadIdx.x;
    __shared__ __attribute__((aligned(16))) __bf16 As[128 * 64];
    __shared__ __attribute__((aligned(16))) __bf16 Bs[128 * 64];
    const int lane = tid & 63, wv = tid >> 6, wm = wv >> 1, wn = wv & 1;
    const int n16 = lane & 15, quad = lane >> 4;

    const int r  = tid >> 3;         // staging row 0..31
    const int c8 = (tid & 7) * 8;    // staging col (elems)
    const __bf16* ag = A  + ((size_t)(bm * 128 + r)) * INQ + c8;
    const __bf16* bg = Bw + ((size_t)(bn * 128 + r)) * INQ + c8;
    __bf16* as_dst = As + r * 64 + c8;
    __bf16* bs_dst = Bs + r * 64 + c8;

    f32x4 acc[4][4];
    for (int mt = 0; mt < 4; ++mt)
        for (int nt = 0; nt < 4; ++nt) acc[mt][nt] = f32x4{0.f, 0.f, 0.f, 0.f};

    for (int kt = 0; kt < 96; ++kt) {
        #pragma unroll
        for (int i = 0; i < 4; ++i) {
            ASYNC_CP16(ag + (size_t)i * 32 * INQ, as_dst + i * 32 * 64);
            ASYNC_CP16(bg + (size_t)i * 32 * INQ, bs_dst + i * 32 * 64);
        }
        ag += 64;
        bg += 64;
        __syncthreads();
        #pragma unroll
        for (int kk = 0; kk < 2; ++kk) {
            bf16x8 af[4], bf[4];
            #pragma unroll
            for (int mt = 0; mt < 4; ++mt)
                af[mt] = *(const bf16x8*)&As[(wm * 64 + mt * 16 + n16) * 64 + kk * 32 + quad * 8];
            #pragma unroll
            for (int nt = 0; nt < 4; ++nt)
                bf[nt] = *(const bf16x8*)&Bs[(wn * 64 + nt * 16 + n16) * 64 + kk * 32 + quad * 8];
            #pragma unroll
            for (int mt = 0; mt < 4; ++mt)
                #pragma unroll
                for (int nt = 0; nt < 4; ++nt) acc[mt][nt] = MFMA16(af[mt], bf[nt], acc[mt][nt]);
        }
        __syncthreads();
    }
    #pragma unroll
    for (int nt = 0; nt < 4; ++nt) {
        int n = bn * 128 + wn * 64 + nt * 16 + n16;
        float bvv = bih[n];
        #pragma unroll
        for (int mt = 0; mt < 4; ++mt) {
            int m0 = bm * 128 + wm * 64 + mt * 16 + quad * 4;
            #pragma unroll
            for (int i = 0; i < 4; ++i)
                gx[(size_t)(m0 + i) * G3 + n] = (__bf16)(acc[mt][nt][i] + bvv);
        }
    }
}

// =====================================================================
// Kernel 4: persistent GRU scan, FENCE-FREE device barrier.
// All cross-block data (h) moves via agent-scope relaxed atomics (sc0 sc1,
// cache-bypassing, executed at the coherence point), so no buffer_wbl2 /
// buffer_inv is ever needed. __syncthreads' vmcnt drain orders store->arrive.
// bar layout (128B lines): cnt[16] @ i*32, master @ 16*32, gen @ 17*32.
// =====================================================================
__global__ __launch_bounds__(256) void gru_kernel(const __bf16* __restrict__ gx,
                                                  const float* __restrict__ Whh,
                                                  const float* __restrict__ bhh,
                                                  const float* __restrict__ h0,
                                                  __bf16* __restrict__ hbuf,
                                                  unsigned* __restrict__ bar,
                                                  float* __restrict__ out) {
    const int blk = blockIdx.x;   // 384
    const int tid = threadIdx.x;
    const int u0 = blk * 4;
    constexpr int LDW = 1560;     // padded row stride (elems)
    __shared__ __attribute__((aligned(16))) __bf16 Wl[12][LDW];  // rows: gate*4+du
    __shared__ __attribute__((aligned(16))) __bf16 hl[4][LDW];   // [b][k]
    __shared__ float part[4][4][16];                             // [wave][batch][row j]
    __shared__ unsigned short hpack[4][4];                       // [batch][du] bf16 bits

    unsigned* cnt    = bar + (blk & 15) * 32;
    unsigned* master = bar + 16 * 32;
    unsigned* genp   = bar + 17 * 32;

    // fence-free barrier: generation g (1-based, monotone).
    auto bar_sync = [&](unsigned g) {
        __syncthreads();   // drains vmcnt -> block's atomic h-stores acked at LLC
        if (tid == 0) {
            unsigned old = __hip_atomic_fetch_add(cnt, 1u, __ATOMIC_RELAXED,
                                                  __HIP_MEMORY_SCOPE_AGENT);
            if (old + 1 == 24u * g) {
                unsigned mo = __hip_atomic_fetch_add(master, 1u, __ATOMIC_RELAXED,
                                                     __HIP_MEMORY_SCOPE_AGENT);
                if (mo + 1 == 16u * g)
                    __hip_atomic_store(genp, g, __ATOMIC_RELAXED, __HIP_MEMORY_SCOPE_AGENT);
            }
            while (__hip_atomic_load(genp, __ATOMIC_RELAXED, __HIP_MEMORY_SCOPE_AGENT) < g)
                __builtin_amdgcn_s_sleep(1);
        }
        __syncthreads();
    };

    // load Whh slice (fp32 -> bf16), once
    for (int idx = tid; idx < 12 * HID; idx += 256) {
        int j = idx / HID, cc = idx % HID;
        int g = j >> 2, du = j & 3;
        Wl[j][cc] = (__bf16)Whh[(size_t)(g * HID + u0 + du) * HID + cc];
    }
    // init hbuf[0] from h0 via agent atomic stores (visible w/o fences)
    {
        u64* hb8 = (u64*)hbuf;
        for (int i = blk * 256 + tid; i < 1536; i += 384 * 256) {
            float4 v = *(const float4*)(h0 + i * 4);
            __hip_atomic_store(hb8 + i, pack4bf(v.x, v.y, v.z, v.w),
                               __ATOMIC_RELAXED, __HIP_MEMORY_SCOPE_AGENT);
        }
    }

    float hreg = 0.f;
    const int gb = tid >> 2, gu = tid & 3;  // gate-thread batch / unit-offset (tid<16)
    float bhr = 0.f, bhz = 0.f, bhn = 0.f;
    if (tid < 16) {
        hreg = h0[gb * HID + u0 + gu];
        bhr = bhh[u0 + gu];
        bhz = bhh[HID + u0 + gu];
        bhn = bhh[2 * HID + u0 + gu];
    }

    bar_sync(1);

    const int lane = tid & 63, wvi = tid >> 6;
    const int n16 = lane & 15, quad = lane >> 4;
    const int kbase = wvi * 384;
    const int wr = (n16 < 12) ? n16 : 0;   // clamp: rows >=12 produce unused lanes
    const int hr = n16 & 3;                // clamp: A rows >=4 produce unused D rows

    for (int t = 0; t < TN; ++t) {
        // stage h[t] -> LDS via cache-bypassing 8B atomic loads (coalesced)
        const u64* hs8 = (const u64*)(hbuf + (size_t)(t & 1) * INQ);
        #pragma unroll
        for (int j = tid; j < 1536; j += 256) {
            u64 v = __hip_atomic_load(hs8 + j, __ATOMIC_RELAXED, __HIP_MEMORY_SCOPE_AGENT);
            int bb = j / 384, cc = j % 384;
            *(u64*)&hl[bb][cc * 4] = v;
        }
        __syncthreads();

        f32x4 acc = f32x4{0.f, 0.f, 0.f, 0.f};
        #pragma unroll
        for (int ks = 0; ks < 12; ++ks) {
            int k = kbase + ks * 32 + quad * 8;
            bf16x8 av = *(const bf16x8*)&hl[hr][k];
            bf16x8 bv = *(const bf16x8*)&Wl[wr][k];
            acc = MFMA16(av, bv, acc);
        }
        if (quad == 0) {
            #pragma unroll
            for (int i = 0; i < 4; ++i) part[wvi][i][n16] = acc[i];
        }
        __syncthreads();

        if (tid < 16) {
            float gr = 0.f, gz = 0.f, gn = 0.f;
            #pragma unroll
            for (int w = 0; w < 4; ++w) {
                gr += part[w][gb][gu];
                gz += part[w][gb][4 + gu];
                gn += part[w][gb][8 + gu];
            }
            const __bf16* gxr = gx + (size_t)(gb * TN + t) * G3;
            float xr = (float)gxr[u0 + gu];
            float xz = (float)gxr[HID + u0 + gu];
            float xn = (float)gxr[2 * HID + u0 + gu];
            float rr = 1.f / (1.f + __expf(-(xr + gr + bhr)));
            float zz = 1.f / (1.f + __expf(-(xz + gz + bhz)));
            float nn = tanhf(xn + rr * (gn + bhn));
            float hn = (1.f - zz) * nn + zz * hreg;
            hreg = hn;
            union { __bf16 h; unsigned short us; } cv;
            cv.h = (__bf16)hn;
            hpack[gb][gu] = cv.us;   // same-wave LDS exchange (tid<16 all in wave 0)
            int uu = u0 + gu;
            out[((size_t)(gb * CN + uu / FN) * TN + t) * FN + (uu % FN)] = hn;
            if (gu == 0) {   // pack 4 bf16 -> one 8B agent atomic store
                u64 p = (u64)hpack[gb][0] | ((u64)hpack[gb][1] << 16) |
                        ((u64)hpack[gb][2] << 32) | ((u64)hpack[gb][3] << 48);
                u64* hd8 = (u64*)(hbuf + (size_t)((t + 1) & 1) * INQ);
                __hip_atomic_store(hd8 + gb * 384 + blk, p,
                                   __ATOMIC_RELAXED, __HIP_MEMORY_SCOPE_AGENT);
            }
        }
        bar_sync((unsigned)(t + 2));
    }
    if (tid < 16) out[(size_t)BN * CN * TN * FN + gb * HID + u0 + gu] = hreg;
}

// =====================================================================
extern "C" void kernel_launch(void* const* d_in, const int* in_sizes, int n_in,
                              void* d_out, int out_size, void* d_ws, size_t ws_size,
                              hipStream_t stream) {
    const float* x   = (const float*)d_in[0];
    const float* h0  = (const float*)d_in[1];
    const float* Wq  = (const float*)d_in[2];
    const float* bq  = (const float*)d_in[3];
    const float* Wk  = (const float*)d_in[4];
    const float* bk  = (const float*)d_in[5];
    const float* Wv  = (const float*)d_in[6];
    const float* bv  = (const float*)d_in[7];
    const float* Wih = (const float*)d_in[8];
    const float* Whh = (const float*)d_in[9];
    const float* bih = (const float*)d_in[10];
    const float* bhh = (const float*)d_in[11];
    float* out = (float*)d_out;
    char* ws = (char*)d_ws;
    __bf16* seqB = (__bf16*)(ws + OFF_SEQ);
    __bf16* WihB = (__bf16*)(ws + OFF_WIH);
    __bf16* gxB  = (__bf16*)(ws + OFF_GX);
    __bf16* hbuf = (__bf16*)(ws + OFF_H);
    unsigned* bar = (unsigned*)(ws + OFF_BAR);

    hipMemsetAsync((void*)bar, 0, 4096, stream);  // zero barrier state every launch
    hipLaunchKernelGGL(cvt_wih_kernel, dim3(2048), dim3(256), 0, stream, Wih, WihB);
    hipLaunchKernelGGL(conv_attn_kernel, dim3(4096), dim3(256), 0, stream,
                       x, Wq, bq, Wk, bk, Wv, bv, seqB);
    hipLaunchKernelGGL(gemm_kernel, dim3(36, 32), dim3(256), 0, stream, seqB, WihB, bih, gxB);

    void* args[] = {(void*)&gxB, (void*)&Whh, (void*)&bhh, (void*)&h0,
                    (void*)&hbuf, (void*)&bar, (void*)&out};
    hipLaunchCooperativeKernel((void*)gru_kernel, dim3(384), dim3(256), args, 0, stream);
}